// Round 7
// baseline (239.372 us; speedup 1.0000x reference)
//
#include <hip/hip_runtime.h>

#define FEAT 64
#define NGRAPH 64
#define POOL_CHUNKS 8
#define LAYER_BLOCKS 2048

// ---------------------------------------------------------------------------
// Layer-carried tensor: u[i] = bf16( dinv[i] * x_layer[i] )  (N x 64, packed
// 2 bf16 per u32 -> N*32 words). Per layer (agg-first reordering of GCN):
//   s[i]  = sum_{e: src->i} u[src] + u[i]            (gather, f32 acc)
//   y[i]  = dinv[i] * (s[i] @ W) + b                  (W in registers)
//   mid:  u'[i] = bf16(dinv[i] * relu(y));  last: h[i] = y (f32, for pool)
// ---------------------------------------------------------------------------
// Workspace layout (4-byte units):
//   xbuf    [N*64]  f32   layer-3 output h3 (pool input)
//   u       [N*32]  u32   bf16x2 layer-carried tensor
//   rowptr  [N+1]   i32   CSR row offsets (by dst)
//   rank    [E]     i32   per-edge rank within its dst run (from k_count)
//   cnt_int [N]     i32   in-degree counts
//   dinv    [N]     f32   rsqrt(1 + in-degree)
//   bsum    [256]   i32   per-block scan partials
//   csr     [E]     u32   packed {wbit<<16 | src}  (src<65536, w in {0,1})
//   pooled  [64*64] f32   per-graph feature sums
//   gcnt    [64]    f32   per-graph node counts
//   flag    [1]     i32   supernode_mask storage-layout flag
// ---------------------------------------------------------------------------

__device__ __forceinline__ unsigned int pack_bf16(float a, float b) {
    unsigned int ua = __float_as_uint(a), ub = __float_as_uint(b);
    ua = (ua + 0x7FFFu + ((ua >> 16) & 1u)) >> 16;       // RNE
    ub = (ub + 0x7FFFu + ((ub >> 16) & 1u)) >> 16;
    return ua | (ub << 16);
}
__device__ __forceinline__ float bf_lo(unsigned int w) {
    return __uint_as_float(w << 16);
}
__device__ __forceinline__ float bf_hi(unsigned int w) {
    return __uint_as_float(w & 0xFFFF0000u);
}

__global__ __launch_bounds__(256) void k_init(int* __restrict__ cnt_int,
                                              float* __restrict__ pooled,
                                              int* __restrict__ flag, int N) {
    int i = blockIdx.x * 256 + threadIdx.x;
    if (i < N) cnt_int[i] = 0;
    if (i < NGRAPH * FEAT) pooled[i] = 0.f;
    if (i == 0) *flag = 0;
}

// Detect how the bool supernode_mask was pushed to device.
__global__ __launch_bounds__(256) void k_detect(const unsigned int* __restrict__ m,
                                                int nwords, int* __restrict__ flag) {
    int i = blockIdx.x * 256 + threadIdx.x;
    if (i >= nwords) return;
    unsigned int w = m[i];
    if (w == 0x3F800000u) atomicOr(flag, 2);
    else if (w > 1u) atomicOr(flag, 1);
}

__device__ __forceinline__ bool read_mask(const void* sm, int i, int fl) {
    if (fl & 2) return ((const float*)sm)[i] != 0.f;
    if (fl & 1) return ((const unsigned char*)sm)[i] != 0;
    return ((const int*)sm)[i] != 0;
}

// count in-degree AND capture each edge's rank within its dst run.
__global__ __launch_bounds__(256) void k_count(const int* __restrict__ ei,
                                               int* __restrict__ cnt_int,
                                               int* __restrict__ rank, int E) {
    int e = blockIdx.x * 256 + threadIdx.x;
    if (e >= E) return;
    rank[e] = atomicAdd(&cnt_int[ei[E + e]], 1);
}

// --- 3-phase parallel exclusive scan ---------------------------------------
__global__ __launch_bounds__(256) void k_scan1(const int* __restrict__ cnt,
                                               int* __restrict__ rowptr,
                                               int* __restrict__ bsum, int N) {
    __shared__ int woff[4];
    int t = threadIdx.x, lane = t & 63, wid = t >> 6;
    int i = blockIdx.x * 256 + t;
    int orig = (i < N) ? cnt[i] : 0;
    int v = orig;
#pragma unroll
    for (int off = 1; off < 64; off <<= 1) {
        int u = __shfl_up(v, off);
        if (lane >= off) v += u;
    }
    if (lane == 63) woff[wid] = v;
    __syncthreads();
    if (t == 0) {
        int a = 0;
#pragma unroll
        for (int w = 0; w < 4; ++w) { int b = woff[w]; woff[w] = a; a += b; }
    }
    __syncthreads();
    int excl = woff[wid] + v - orig;
    if (i < N) rowptr[i] = excl;
    if (t == 255) bsum[blockIdx.x] = woff[3] + v;
}

__global__ __launch_bounds__(256) void k_scan2(int* __restrict__ bsum, int nb) {
    __shared__ int woff[4];
    int t = threadIdx.x, lane = t & 63, wid = t >> 6;
    int orig = (t < nb) ? bsum[t] : 0;
    int v = orig;
#pragma unroll
    for (int off = 1; off < 64; off <<= 1) {
        int u = __shfl_up(v, off);
        if (lane >= off) v += u;
    }
    if (lane == 63) woff[wid] = v;
    __syncthreads();
    if (t == 0) {
        int a = 0;
#pragma unroll
        for (int w = 0; w < 4; ++w) { int b = woff[w]; woff[w] = a; a += b; }
    }
    __syncthreads();
    if (t < nb) bsum[t] = woff[wid] + v - orig;
}

__global__ __launch_bounds__(256) void k_scan3(const int* __restrict__ cnt,
                                               const int* __restrict__ bsum,
                                               int* __restrict__ rowptr,
                                               float* __restrict__ dinv,
                                               int N, int E) {
    int i = blockIdx.x * 256 + threadIdx.x;
    if (i >= N) return;
    rowptr[i] += bsum[blockIdx.x];
    dinv[i] = rsqrtf((float)cnt[i] + 1.0f);
    if (i == 0) rowptr[N] = E;
}

// csr[rowptr[dst]+rank] = src | (w!=0)<<16      (single scattered 4B store)
__global__ __launch_bounds__(256) void k_fill(const int* __restrict__ ei,
                                              const float* __restrict__ emask,
                                              const int* __restrict__ rowptr,
                                              const int* __restrict__ rank,
                                              unsigned int* __restrict__ csr, int E) {
    int e = blockIdx.x * 256 + threadIdx.x;
    if (e >= E) return;
    int dst = ei[E + e];
    unsigned int word = (unsigned int)ei[e];
    if (emask[e] != 0.f) word |= 0x10000u;
    csr[rowptr[dst] + rank[e]] = word;
}

// Wave per node, 4 edge-groups x 16 feature-quarter lanes.
// u0[i] = bf16( dinv[i] * (supernode ? sum_{w=1} x[src] : x[i]) )
__global__ __launch_bounds__(256) void k_sup(const float* __restrict__ x,
                                             const int* __restrict__ rowptr,
                                             const unsigned int* __restrict__ csr,
                                             const void* __restrict__ sm,
                                             const int* __restrict__ flag,
                                             const float* __restrict__ dinv,
                                             unsigned int* __restrict__ u, int N) {
    int t = blockIdx.x * 256 + threadIdx.x;
    int i = t >> 6, lane = t & 63;
    if (i >= N) return;
    int g = lane >> 4, q = lane & 15;
    int fl = *flag;
    float4 acc;
    if (read_mask(sm, i, fl)) {
        int r0 = rowptr[i], r1 = rowptr[i + 1];
        acc.x = 0.f; acc.y = 0.f; acc.z = 0.f; acc.w = 0.f;
        for (int j0 = r0; j0 < r1; j0 += 64) {
            int cnt = min(64, r1 - j0);
            unsigned int w_l = (lane < cnt) ? csr[j0 + lane] : 0u;
            int rounds4 = (cnt + 3) & ~3;
#pragma unroll 2
            for (int j = 0; j < rounds4; j += 4) {
                unsigned int wd = __shfl(w_l, j + g);
                if (wd & 0x10000u) {
                    int s = (int)(wd & 0xFFFFu);
                    const float4 v = *(const float4*)(x + (size_t)s * FEAT + q * 4);
                    acc.x += v.x; acc.y += v.y; acc.z += v.z; acc.w += v.w;
                }
            }
        }
#pragma unroll
        for (int m = 16; m < 64; m <<= 1) {
            acc.x += __shfl_xor(acc.x, m);
            acc.y += __shfl_xor(acc.y, m);
            acc.z += __shfl_xor(acc.z, m);
            acc.w += __shfl_xor(acc.w, m);
        }
    } else {
        acc = *(const float4*)(x + (size_t)i * FEAT + q * 4);
    }
    if (g == 0) {
        float dd = dinv[i];
        uint2 p;
        p.x = pack_bf16(acc.x * dd, acc.y * dd);
        p.y = pack_bf16(acc.z * dd, acc.w * dd);
        *(uint2*)(u + (size_t)i * 32 + q * 2) = p;
    }
}

// Fused layer: wave per node (grid-stride).
//   s = sum_e u[src] + u[i]  (4 groups x 16 lanes, f32 acc)
//   y[lane] = dinv[i] * (s @ W[:,lane]) + b[lane]     (W column in registers)
//   mode 0: u_out[i] = bf16(dinv[i]*relu(y));  mode 1: h_out[i] = y
__global__ __launch_bounds__(256, 4) void k_layer(const unsigned int* __restrict__ u,
                                                  const float* __restrict__ W,
                                                  const float* __restrict__ bias,
                                                  const float* __restrict__ dinv,
                                                  const int* __restrict__ rowptr,
                                                  const unsigned int* __restrict__ csr,
                                                  unsigned int* __restrict__ u_out,
                                                  float* __restrict__ h_out,
                                                  int N, int mode) {
    __shared__ float s_lds[4][64];
    int t = threadIdx.x, lane = t & 63, wid = t >> 6;
    int g = lane >> 4, q = lane & 15;
    float w[64];
#pragma unroll
    for (int k = 0; k < 64; ++k) w[k] = W[k * 64 + lane];
    float bl_ = bias[lane];
    for (int i = blockIdx.x * 4 + wid; i < N; i += LAYER_BLOCKS * 4) {
        int r0 = rowptr[i], r1 = rowptr[i + 1];
        float4 acc = {0.f, 0.f, 0.f, 0.f};
        if (g == 0) {  // self term u[i], counted once
            const uint2 v = *(const uint2*)(u + (size_t)i * 32 + q * 2);
            acc.x += bf_lo(v.x); acc.y += bf_hi(v.x);
            acc.z += bf_lo(v.y); acc.w += bf_hi(v.y);
        }
        for (int j0 = r0; j0 < r1; j0 += 64) {
            int cnt = min(64, r1 - j0);
            int s_l = (lane < cnt) ? (int)(csr[j0 + lane] & 0xFFFFu) : 0;
            int rounds4 = (cnt + 3) & ~3;
#pragma unroll 4
            for (int j = 0; j < rounds4; j += 4) {
                int jj = j + g;
                int s = __shfl(s_l, jj);
                if (jj < cnt) {
                    const uint2 v = *(const uint2*)(u + (size_t)s * 32 + q * 2);
                    acc.x += bf_lo(v.x); acc.y += bf_hi(v.x);
                    acc.z += bf_lo(v.y); acc.w += bf_hi(v.y);
                }
            }
        }
#pragma unroll
        for (int m = 16; m < 64; m <<= 1) {
            acc.x += __shfl_xor(acc.x, m);
            acc.y += __shfl_xor(acc.y, m);
            acc.z += __shfl_xor(acc.z, m);
            acc.w += __shfl_xor(acc.w, m);
        }
        if (g == 0) *(float4*)(&s_lds[wid][q * 4]) = acc;
        // per-wave LDS RAW: compiler inserts lgkmcnt wait before reads
        float y = 0.f;
#pragma unroll
        for (int k4 = 0; k4 < 16; ++k4) {
            const float4 sv = *(const float4*)(&s_lds[wid][k4 * 4]);
            y += sv.x * w[k4 * 4 + 0] + sv.y * w[k4 * 4 + 1] +
                 sv.z * w[k4 * 4 + 2] + sv.w * w[k4 * 4 + 3];
        }
        float dd = dinv[i];
        y = y * dd + bl_;
        if (mode == 0) {
            y = fmaxf(y, 0.f);
            float up = y * dd;
            float other = __shfl_xor(up, 1);
            if ((lane & 1) == 0)
                u_out[(size_t)i * 32 + (lane >> 1)] = pack_bf16(up, other);
        } else {
            h_out[(size_t)i * FEAT + lane] = y;
        }
    }
}

__device__ __forceinline__ int lbound(const int* a, int n, int key) {
    int lo = 0, hi = n;
    while (lo < hi) {
        int mid = (lo + hi) >> 1;
        if (a[mid] < key) lo = mid + 1; else hi = mid;
    }
    return lo;
}

// 8 blocks per graph; partial sums atomically added to pooled.
__global__ __launch_bounds__(256) void k_pool(const float* __restrict__ xbuf,
                                              const int* __restrict__ batch,
                                              float* __restrict__ pooled,
                                              float* __restrict__ gcnt, int N) {
    int g = blockIdx.x >> 3, c = blockIdx.x & (POOL_CHUNKS - 1);
    int lo = lbound(batch, N, g);
    int hi = lbound(batch, N, g + 1);
    int len = hi - lo;
    int t = threadIdx.x, lane = t & 63, sub = t >> 6;
    if (c == 0 && t == 0) gcnt[g] = (float)len;
    int a = lo + (int)(((long long)len * c) / POOL_CHUNKS);
    int bnd = lo + (int)(((long long)len * (c + 1)) / POOL_CHUNKS);
    float s = 0.f;
    for (int i = a + sub; i < bnd; i += 4) s += xbuf[(size_t)i * FEAT + lane];
    __shared__ float red[4][64];
    red[sub][lane] = s;
    __syncthreads();
    if (sub == 0) {
        float tot = red[0][lane] + red[1][lane] + red[2][lane] + red[3][lane];
        unsafeAtomicAdd(&pooled[g * FEAT + lane], tot);
    }
}

// out[g][cls] = (pooled[g]/gcnt[g]) . Wl[:,cls] + bl[cls]
__global__ __launch_bounds__(640) void k_logits(const float* __restrict__ pooled,
                                                const float* __restrict__ gcnt,
                                                const float* __restrict__ Wl,
                                                const float* __restrict__ bl,
                                                float* __restrict__ out) {
    int t = threadIdx.x;
    if (t >= NGRAPH * 10) return;
    int g = t / 10, cls = t % 10;
    float inv = 1.f / fmaxf(gcnt[g], 1.f);
    float s = 0.f;
#pragma unroll
    for (int f = 0; f < 64; ++f) s += pooled[g * 64 + f] * Wl[f * 10 + cls];
    out[t] = s * inv + bl[cls];
}

extern "C" void kernel_launch(void* const* d_in, const int* in_sizes, int n_in,
                              void* d_out, int out_size, void* d_ws, size_t ws_size,
                              hipStream_t stream) {
    const float* x = (const float*)d_in[0];
    const int* ei = (const int*)d_in[1];
    const void* sm = d_in[2];
    const float* emask = (const float*)d_in[3];
    const int* batch = (const int*)d_in[4];
    const float* W1 = (const float*)d_in[5];
    const float* b1 = (const float*)d_in[6];
    const float* W2 = (const float*)d_in[7];
    const float* b2 = (const float*)d_in[8];
    const float* W3 = (const float*)d_in[9];
    const float* b3 = (const float*)d_in[10];
    const float* Wl = (const float*)d_in[11];
    const float* bl = (const float*)d_in[12];

    const int N = in_sizes[0] / FEAT;   // 50000 (< 65536: src fits in u16)
    const int E = in_sizes[1] / 2;

    float* wsf = (float*)d_ws;
    size_t off = 0;
    float* xbuf = wsf + off;          off += (size_t)N * FEAT;
    unsigned int* u = (unsigned int*)(wsf + off);  off += (size_t)N * 32;
    unsigned int* u2 = (unsigned int*)(wsf + off); off += (size_t)N * 32;
    int* rowptr = (int*)(wsf + off);  off += N + 1;
    int* rank = (int*)(wsf + off);    off += E;
    int* cnt_int = (int*)(wsf + off); off += N;
    float* dinv = wsf + off;          off += N;
    int* bsum = (int*)(wsf + off);    off += 256;
    unsigned int* csr = (unsigned int*)(wsf + off); off += E;
    float* pooled = wsf + off;        off += NGRAPH * FEAT;
    float* gcnt = wsf + off;          off += NGRAPH;
    int* flag = (int*)(wsf + off);

    const int nblocks = (N + 255) / 256;
    const int eblocks = (E + 255) / 256;
    const int wblocks = (N * 64 + 255) / 256;
    const int detect_blocks = (N / 4 + 255) / 256;

    k_init<<<nblocks, 256, 0, stream>>>(cnt_int, pooled, flag, N);
    k_detect<<<detect_blocks, 256, 0, stream>>>((const unsigned int*)sm, N / 4, flag);
    k_count<<<eblocks, 256, 0, stream>>>(ei, cnt_int, rank, E);
    k_scan1<<<nblocks, 256, 0, stream>>>(cnt_int, rowptr, bsum, N);
    k_scan2<<<1, 256, 0, stream>>>(bsum, nblocks);
    k_scan3<<<nblocks, 256, 0, stream>>>(cnt_int, bsum, rowptr, dinv, N, E);
    k_fill<<<eblocks, 256, 0, stream>>>(ei, emask, rowptr, rank, csr, E);
    k_sup<<<wblocks, 256, 0, stream>>>(x, rowptr, csr, sm, flag, dinv, u, N);

    // fused gather+GEMM layers (agg-first reordering)
    k_layer<<<LAYER_BLOCKS, 256, 0, stream>>>(u, W1, b1, dinv, rowptr, csr,
                                              u2, (float*)nullptr, N, 0);
    k_layer<<<LAYER_BLOCKS, 256, 0, stream>>>(u2, W2, b2, dinv, rowptr, csr,
                                              u, (float*)nullptr, N, 0);
    k_layer<<<LAYER_BLOCKS, 256, 0, stream>>>(u, W3, b3, dinv, rowptr, csr,
                                              (unsigned int*)nullptr, xbuf, N, 1);

    k_pool<<<NGRAPH * POOL_CHUNKS, 256, 0, stream>>>(xbuf, batch, pooled, gcnt, N);
    k_logits<<<1, 640, 0, stream>>>(pooled, gcnt, Wl, bl, (float*)d_out);
}

// Round 8
// 215.466 us; speedup vs baseline: 1.1110x; 1.1110x over previous
//
#include <hip/hip_runtime.h>

#define FEAT 64
#define NGRAPH 64
#define POOL_CHUNKS 8

typedef short bf16x8 __attribute__((ext_vector_type(8)));
typedef float f32x4 __attribute__((ext_vector_type(4)));
union FragU { uint4 u4; bf16x8 h; };

// ---------------------------------------------------------------------------
// Pipeline (agg math: hd = bf16(dinv_r * (u @ W)); out = (sum_e hd[src]+hd[i])*dd + b)
//   xbuf  [N*64] f32   layer-3 output (pool input)
//   ua,ub [N*32] u32   bf16x2 activations (ping-pong)
//   hd    [N*32] u32   bf16x2 post-GEMM features
//   wbf   [3*2048] u32 WbfT: per-layer transposed bf16 weights, wbf[c][k]
//   rowptr[N+1], rank[E], cnt_int[N], dinv[N], bsum[256], csr[E]
//   pooled[64*64], gcnt[64], flag[1]
// ---------------------------------------------------------------------------

__device__ __forceinline__ unsigned int pack_bf16(float a, float b) {
    unsigned int ua = __float_as_uint(a), ub = __float_as_uint(b);
    ua = (ua + 0x7FFFu + ((ua >> 16) & 1u)) >> 16;       // RNE
    ub = (ub + 0x7FFFu + ((ub >> 16) & 1u)) >> 16;
    return ua | (ub << 16);
}
__device__ __forceinline__ float bf_lo(unsigned int w) {
    return __uint_as_float(w << 16);
}
__device__ __forceinline__ float bf_hi(unsigned int w) {
    return __uint_as_float(w & 0xFFFF0000u);
}

__global__ __launch_bounds__(256) void k_init(int* __restrict__ cnt_int,
                                              float* __restrict__ pooled,
                                              int* __restrict__ flag, int N) {
    int i = blockIdx.x * 256 + threadIdx.x;
    if (i < N) cnt_int[i] = 0;
    if (i < NGRAPH * FEAT) pooled[i] = 0.f;
    if (i == 0) *flag = 0;
}

// WbfT[m][c][k]: packed bf16 pairs (k even|odd), transposed from W[k][c]
__global__ __launch_bounds__(256) void k_wcvt(const float* __restrict__ W1,
                                              const float* __restrict__ W2,
                                              const float* __restrict__ W3,
                                              unsigned int* __restrict__ wt) {
    int t = blockIdx.x * 256 + threadIdx.x;
    if (t >= 3 * 2048) return;
    int m = t >> 11, w = t & 2047;
    int c = w >> 5, kw = w & 31;
    const float* W = (m == 0) ? W1 : ((m == 1) ? W2 : W3);
    wt[t] = pack_bf16(W[(2 * kw) * 64 + c], W[(2 * kw + 1) * 64 + c]);
}

// Detect how the bool supernode_mask was pushed to device.
__global__ __launch_bounds__(256) void k_detect(const unsigned int* __restrict__ m,
                                                int nwords, int* __restrict__ flag) {
    int i = blockIdx.x * 256 + threadIdx.x;
    if (i >= nwords) return;
    unsigned int w = m[i];
    if (w == 0x3F800000u) atomicOr(flag, 2);
    else if (w > 1u) atomicOr(flag, 1);
}

__device__ __forceinline__ bool read_mask(const void* sm, int i, int fl) {
    if (fl & 2) return ((const float*)sm)[i] != 0.f;
    if (fl & 1) return ((const unsigned char*)sm)[i] != 0;
    return ((const int*)sm)[i] != 0;
}

// count in-degree AND capture each edge's rank within its dst run.
__global__ __launch_bounds__(256) void k_count(const int* __restrict__ ei,
                                               int* __restrict__ cnt_int,
                                               int* __restrict__ rank, int E) {
    int e = blockIdx.x * 256 + threadIdx.x;
    if (e >= E) return;
    rank[e] = atomicAdd(&cnt_int[ei[E + e]], 1);
}

// --- 3-phase parallel exclusive scan ---------------------------------------
__global__ __launch_bounds__(256) void k_scan1(const int* __restrict__ cnt,
                                               int* __restrict__ rowptr,
                                               int* __restrict__ bsum, int N) {
    __shared__ int woff[4];
    int t = threadIdx.x, lane = t & 63, wid = t >> 6;
    int i = blockIdx.x * 256 + t;
    int orig = (i < N) ? cnt[i] : 0;
    int v = orig;
#pragma unroll
    for (int off = 1; off < 64; off <<= 1) {
        int u = __shfl_up(v, off);
        if (lane >= off) v += u;
    }
    if (lane == 63) woff[wid] = v;
    __syncthreads();
    if (t == 0) {
        int a = 0;
#pragma unroll
        for (int w = 0; w < 4; ++w) { int b = woff[w]; woff[w] = a; a += b; }
    }
    __syncthreads();
    int excl = woff[wid] + v - orig;
    if (i < N) rowptr[i] = excl;
    if (t == 255) bsum[blockIdx.x] = woff[3] + v;
}

__global__ __launch_bounds__(256) void k_scan2(int* __restrict__ bsum, int nb) {
    __shared__ int woff[4];
    int t = threadIdx.x, lane = t & 63, wid = t >> 6;
    int orig = (t < nb) ? bsum[t] : 0;
    int v = orig;
#pragma unroll
    for (int off = 1; off < 64; off <<= 1) {
        int u = __shfl_up(v, off);
        if (lane >= off) v += u;
    }
    if (lane == 63) woff[wid] = v;
    __syncthreads();
    if (t == 0) {
        int a = 0;
#pragma unroll
        for (int w = 0; w < 4; ++w) { int b = woff[w]; woff[w] = a; a += b; }
    }
    __syncthreads();
    if (t < nb) bsum[t] = woff[wid] + v - orig;
}

__global__ __launch_bounds__(256) void k_scan3(const int* __restrict__ cnt,
                                               const int* __restrict__ bsum,
                                               int* __restrict__ rowptr,
                                               float* __restrict__ dinv,
                                               int N, int E) {
    int i = blockIdx.x * 256 + threadIdx.x;
    if (i >= N) return;
    rowptr[i] += bsum[blockIdx.x];
    dinv[i] = rsqrtf((float)cnt[i] + 1.0f);
    if (i == 0) rowptr[N] = E;
}

// csr[rowptr[dst]+rank] = src | (w!=0)<<16      (single scattered 4B store)
__global__ __launch_bounds__(256) void k_fill(const int* __restrict__ ei,
                                              const float* __restrict__ emask,
                                              const int* __restrict__ rowptr,
                                              const int* __restrict__ rank,
                                              unsigned int* __restrict__ csr, int E) {
    int e = blockIdx.x * 256 + threadIdx.x;
    if (e >= E) return;
    int dst = ei[E + e];
    unsigned int word = (unsigned int)ei[e];
    if (emask[e] != 0.f) word |= 0x10000u;
    csr[rowptr[dst] + rank[e]] = word;
}

// Wave per node, 4 edge-groups x 16 feature-quarter lanes.
// u0[i] = bf16( supernode ? sum_{w=1} x[src] : x[i] )
__global__ __launch_bounds__(256) void k_sup(const float* __restrict__ x,
                                             const int* __restrict__ rowptr,
                                             const unsigned int* __restrict__ csr,
                                             const void* __restrict__ sm,
                                             const int* __restrict__ flag,
                                             unsigned int* __restrict__ u, int N) {
    int t = blockIdx.x * 256 + threadIdx.x;
    int i = t >> 6, lane = t & 63;
    if (i >= N) return;
    int g = lane >> 4, q = lane & 15;
    int fl = *flag;
    float4 acc;
    if (read_mask(sm, i, fl)) {
        int r0 = rowptr[i], r1 = rowptr[i + 1];
        acc.x = 0.f; acc.y = 0.f; acc.z = 0.f; acc.w = 0.f;
        for (int j0 = r0; j0 < r1; j0 += 64) {
            int cnt = min(64, r1 - j0);
            unsigned int w_l = (lane < cnt) ? csr[j0 + lane] : 0u;
            int rounds4 = (cnt + 3) & ~3;
#pragma unroll 2
            for (int j = 0; j < rounds4; j += 4) {
                unsigned int wd = __shfl(w_l, j + g);
                if (wd & 0x10000u) {
                    int s = (int)(wd & 0xFFFFu);
                    const float4 v = *(const float4*)(x + (size_t)s * FEAT + q * 4);
                    acc.x += v.x; acc.y += v.y; acc.z += v.z; acc.w += v.w;
                }
            }
        }
#pragma unroll
        for (int m = 16; m < 64; m <<= 1) {
            acc.x += __shfl_xor(acc.x, m);
            acc.y += __shfl_xor(acc.y, m);
            acc.z += __shfl_xor(acc.z, m);
            acc.w += __shfl_xor(acc.w, m);
        }
    } else {
        acc = *(const float4*)(x + (size_t)i * FEAT + q * 4);
    }
    if (g == 0) {
        uint2 p;
        p.x = pack_bf16(acc.x, acc.y);
        p.y = pack_bf16(acc.z, acc.w);
        *(uint2*)(u + (size_t)i * 32 + q * 2) = p;
    }
}

// MFMA GEMM: hd[r][:] = bf16( dinv[r] * (u[r][:] @ W) ), one 16x64 tile/wave.
// A frag: row=lane&15, k=8*(lane>>4)+j.  B frag (from WbfT[c][k]): col=lane&15.
// D frag: col=lane&15, row=4*(lane>>4)+reg.
__global__ __launch_bounds__(256) void k_gemm_mfma(const unsigned int* __restrict__ u_in,
                                                   const unsigned int* __restrict__ wbfT,
                                                   const float* __restrict__ dinv,
                                                   unsigned int* __restrict__ hd, int N) {
    int wid = threadIdx.x >> 6, lane = threadIdx.x & 63;
    int row0 = (blockIdx.x * 4 + wid) * 16;
    if (row0 >= N) return;
    int r = lane & 15, half = lane >> 4;
    f32x4 acc0 = {0.f, 0.f, 0.f, 0.f}, acc1 = acc0, acc2 = acc0, acc3 = acc0;
#pragma unroll
    for (int ks = 0; ks < 2; ++ks) {
        FragU a;
        a.u4 = *(const uint4*)(u_in + (size_t)(row0 + r) * 32 + ks * 16 + half * 4);
        FragU b0, b1, b2, b3;
        b0.u4 = *(const uint4*)(wbfT + (0 * 16 + r) * 32 + ks * 16 + half * 4);
        b1.u4 = *(const uint4*)(wbfT + (1 * 16 + r) * 32 + ks * 16 + half * 4);
        b2.u4 = *(const uint4*)(wbfT + (2 * 16 + r) * 32 + ks * 16 + half * 4);
        b3.u4 = *(const uint4*)(wbfT + (3 * 16 + r) * 32 + ks * 16 + half * 4);
        acc0 = __builtin_amdgcn_mfma_f32_16x16x32_bf16(a.h, b0.h, acc0, 0, 0, 0);
        acc1 = __builtin_amdgcn_mfma_f32_16x16x32_bf16(a.h, b1.h, acc1, 0, 0, 0);
        acc2 = __builtin_amdgcn_mfma_f32_16x16x32_bf16(a.h, b2.h, acc2, 0, 0, 0);
        acc3 = __builtin_amdgcn_mfma_f32_16x16x32_bf16(a.h, b3.h, acc3, 0, 0, 0);
    }
    float dd0 = dinv[row0 + half * 4 + 0];
    float dd1 = dinv[row0 + half * 4 + 1];
    float dd2 = dinv[row0 + half * 4 + 2];
    float dd3 = dinv[row0 + half * 4 + 3];
#pragma unroll
    for (int t = 0; t < 4; ++t) {
        const f32x4 acc = (t == 0) ? acc0 : (t == 1) ? acc1 : (t == 2) ? acc2 : acc3;
        float v0 = acc[0] * dd0, v1 = acc[1] * dd1, v2 = acc[2] * dd2, v3 = acc[3] * dd3;
        float o0 = __shfl_xor(v0, 1), o1 = __shfl_xor(v1, 1),
              o2 = __shfl_xor(v2, 1), o3 = __shfl_xor(v3, 1);
        if ((r & 1) == 0) {
            size_t base = (size_t)(row0 + half * 4) * 32 + t * 8 + (r >> 1);
            hd[base + 0 * 32] = pack_bf16(v0, o0);
            hd[base + 1 * 32] = pack_bf16(v1, o1);
            hd[base + 2 * 32] = pack_bf16(v2, o2);
            hd[base + 3 * 32] = pack_bf16(v3, o3);
        }
    }
}

// Wave per node, 4 edge-groups x 16 feature-quarter lanes.
// y = dinv[i]*(sum_e hd[src] + hd[i]) + b
// mode 0: u_out = bf16(relu(y));  mode 1: h_out = y (f32)
__global__ __launch_bounds__(256) void k_gather(const unsigned int* __restrict__ hd,
                                                const float* __restrict__ b,
                                                const float* __restrict__ dinv,
                                                const int* __restrict__ rowptr,
                                                const unsigned int* __restrict__ csr,
                                                unsigned int* __restrict__ u_out,
                                                float* __restrict__ h_out,
                                                int N, int mode) {
    int t = blockIdx.x * 256 + threadIdx.x;
    int i = t >> 6, lane = t & 63;
    if (i >= N) return;
    int g = lane >> 4, q = lane & 15;
    int r0 = rowptr[i], r1 = rowptr[i + 1];
    float4 acc = {0.f, 0.f, 0.f, 0.f};
    for (int j0 = r0; j0 < r1; j0 += 64) {
        int cnt = min(64, r1 - j0);
        int s_l = (lane < cnt) ? (int)(csr[j0 + lane] & 0xFFFFu) : 0;
        int rounds4 = (cnt + 3) & ~3;
#pragma unroll 4
        for (int j = 0; j < rounds4; j += 4) {
            int jj = j + g;
            int s = __shfl(s_l, jj);
            if (jj < cnt) {
                const uint2 v = *(const uint2*)(hd + (size_t)s * 32 + q * 2);
                acc.x += bf_lo(v.x); acc.y += bf_hi(v.x);
                acc.z += bf_lo(v.y); acc.w += bf_hi(v.y);
            }
        }
    }
#pragma unroll
    for (int m = 16; m < 64; m <<= 1) {
        acc.x += __shfl_xor(acc.x, m);
        acc.y += __shfl_xor(acc.y, m);
        acc.z += __shfl_xor(acc.z, m);
        acc.w += __shfl_xor(acc.w, m);
    }
    if (g == 0) {
        float dd = dinv[i];
        const uint2 hv = *(const uint2*)(hd + (size_t)i * 32 + q * 2);
        const float4 bv = *(const float4*)(b + q * 4);
        float4 r;
        r.x = (acc.x + bf_lo(hv.x)) * dd + bv.x;
        r.y = (acc.y + bf_hi(hv.x)) * dd + bv.y;
        r.z = (acc.z + bf_lo(hv.y)) * dd + bv.z;
        r.w = (acc.w + bf_hi(hv.y)) * dd + bv.w;
        if (mode == 0) {
            r.x = fmaxf(r.x, 0.f); r.y = fmaxf(r.y, 0.f);
            r.z = fmaxf(r.z, 0.f); r.w = fmaxf(r.w, 0.f);
            uint2 p;
            p.x = pack_bf16(r.x, r.y);
            p.y = pack_bf16(r.z, r.w);
            *(uint2*)(u_out + (size_t)i * 32 + q * 2) = p;
        } else {
            *(float4*)(h_out + (size_t)i * FEAT + q * 4) = r;
        }
    }
}

__device__ __forceinline__ int lbound(const int* a, int n, int key) {
    int lo = 0, hi = n;
    while (lo < hi) {
        int mid = (lo + hi) >> 1;
        if (a[mid] < key) lo = mid + 1; else hi = mid;
    }
    return lo;
}

// 8 blocks per graph; partial sums atomically added to pooled.
__global__ __launch_bounds__(256) void k_pool(const float* __restrict__ xbuf,
                                              const int* __restrict__ batch,
                                              float* __restrict__ pooled,
                                              float* __restrict__ gcnt, int N) {
    int g = blockIdx.x >> 3, c = blockIdx.x & (POOL_CHUNKS - 1);
    int lo = lbound(batch, N, g);
    int hi = lbound(batch, N, g + 1);
    int len = hi - lo;
    int t = threadIdx.x, lane = t & 63, sub = t >> 6;
    if (c == 0 && t == 0) gcnt[g] = (float)len;
    int a = lo + (int)(((long long)len * c) / POOL_CHUNKS);
    int bnd = lo + (int)(((long long)len * (c + 1)) / POOL_CHUNKS);
    float s = 0.f;
    for (int i = a + sub; i < bnd; i += 4) s += xbuf[(size_t)i * FEAT + lane];
    __shared__ float red[4][64];
    red[sub][lane] = s;
    __syncthreads();
    if (sub == 0) {
        float tot = red[0][lane] + red[1][lane] + red[2][lane] + red[3][lane];
        unsafeAtomicAdd(&pooled[g * FEAT + lane], tot);
    }
}

// out[g][cls] = (pooled[g]/gcnt[g]) . Wl[:,cls] + bl[cls]
__global__ __launch_bounds__(640) void k_logits(const float* __restrict__ pooled,
                                                const float* __restrict__ gcnt,
                                                const float* __restrict__ Wl,
                                                const float* __restrict__ bl,
                                                float* __restrict__ out) {
    int t = threadIdx.x;
    if (t >= NGRAPH * 10) return;
    int g = t / 10, cls = t % 10;
    float inv = 1.f / fmaxf(gcnt[g], 1.f);
    float s = 0.f;
#pragma unroll
    for (int f = 0; f < 64; ++f) s += pooled[g * 64 + f] * Wl[f * 10 + cls];
    out[t] = s * inv + bl[cls];
}

extern "C" void kernel_launch(void* const* d_in, const int* in_sizes, int n_in,
                              void* d_out, int out_size, void* d_ws, size_t ws_size,
                              hipStream_t stream) {
    const float* x = (const float*)d_in[0];
    const int* ei = (const int*)d_in[1];
    const void* sm = d_in[2];
    const float* emask = (const float*)d_in[3];
    const int* batch = (const int*)d_in[4];
    const float* W1 = (const float*)d_in[5];
    const float* b1 = (const float*)d_in[6];
    const float* W2 = (const float*)d_in[7];
    const float* b2 = (const float*)d_in[8];
    const float* W3 = (const float*)d_in[9];
    const float* b3 = (const float*)d_in[10];
    const float* Wl = (const float*)d_in[11];
    const float* bl = (const float*)d_in[12];

    const int N = in_sizes[0] / FEAT;   // 50000 (< 65536; 16 | N)
    const int E = in_sizes[1] / 2;

    float* wsf = (float*)d_ws;
    size_t off = 0;
    float* xbuf = wsf + off;          off += (size_t)N * FEAT;
    unsigned int* ua = (unsigned int*)(wsf + off); off += (size_t)N * 32;
    unsigned int* ub = (unsigned int*)(wsf + off); off += (size_t)N * 32;
    unsigned int* hd = (unsigned int*)(wsf + off); off += (size_t)N * 32;
    unsigned int* wbf = (unsigned int*)(wsf + off); off += 3 * 2048;
    int* rowptr = (int*)(wsf + off);  off += N + 1;
    int* rank = (int*)(wsf + off);    off += E;
    int* cnt_int = (int*)(wsf + off); off += N;
    float* dinv = wsf + off;          off += N;
    int* bsum = (int*)(wsf + off);    off += 256;
    unsigned int* csr = (unsigned int*)(wsf + off); off += E;
    float* pooled = wsf + off;        off += NGRAPH * FEAT;
    float* gcnt = wsf + off;          off += NGRAPH;
    int* flag = (int*)(wsf + off);

    const int nblocks = (N + 255) / 256;
    const int eblocks = (E + 255) / 256;
    const int wblocks = (N * 64 + 255) / 256;
    const int gemm_blocks = (N / 16 + 3) / 4;
    const int detect_blocks = (N / 4 + 255) / 256;

    k_init<<<nblocks, 256, 0, stream>>>(cnt_int, pooled, flag, N);
    k_wcvt<<<24, 256, 0, stream>>>(W1, W2, W3, wbf);
    k_detect<<<detect_blocks, 256, 0, stream>>>((const unsigned int*)sm, N / 4, flag);
    k_count<<<eblocks, 256, 0, stream>>>(ei, cnt_int, rank, E);
    k_scan1<<<nblocks, 256, 0, stream>>>(cnt_int, rowptr, bsum, N);
    k_scan2<<<1, 256, 0, stream>>>(bsum, nblocks);
    k_scan3<<<nblocks, 256, 0, stream>>>(cnt_int, bsum, rowptr, dinv, N, E);
    k_fill<<<eblocks, 256, 0, stream>>>(ei, emask, rowptr, rank, csr, E);
    k_sup<<<wblocks, 256, 0, stream>>>(x, rowptr, csr, sm, flag, ua, N);

    // layer 1
    k_gemm_mfma<<<gemm_blocks, 256, 0, stream>>>(ua, wbf + 0 * 2048, dinv, hd, N);
    k_gather<<<wblocks, 256, 0, stream>>>(hd, b1, dinv, rowptr, csr, ub, (float*)nullptr, N, 0);
    // layer 2
    k_gemm_mfma<<<gemm_blocks, 256, 0, stream>>>(ub, wbf + 1 * 2048, dinv, hd, N);
    k_gather<<<wblocks, 256, 0, stream>>>(hd, b2, dinv, rowptr, csr, ua, (float*)nullptr, N, 0);
    // layer 3
    k_gemm_mfma<<<gemm_blocks, 256, 0, stream>>>(ua, wbf + 2 * 2048, dinv, hd, N);
    k_gather<<<wblocks, 256, 0, stream>>>(hd, b3, dinv, rowptr, csr, (unsigned int*)nullptr, xbuf, N, 1);

    k_pool<<<NGRAPH * POOL_CHUNKS, 256, 0, stream>>>(xbuf, batch, pooled, gcnt, N);
    k_logits<<<1, 640, 0, stream>>>(pooled, gcnt, Wl, bl, (float*)d_out);
}

// Round 9
// 210.113 us; speedup vs baseline: 1.1393x; 1.0255x over previous
//
#include <hip/hip_runtime.h>

#define FEAT 64
#define NGRAPH 64
#define POOL_CHUNKS 8

typedef short bf16x8 __attribute__((ext_vector_type(8)));
typedef float f32x4 __attribute__((ext_vector_type(4)));
union FragU { uint4 u4; bf16x8 h; };

// ---------------------------------------------------------------------------
// Pipeline: u0 = bf16(x) (+supernode overwrite); per layer:
//   hd = bf16(dinv_r * (u @ W))          [MFMA GEMM]
//   u' = bf16([relu]( dinv_i*(sum_e hd[src]+hd[i]) + b ))   [8x8 gather]
// pool reads bf16 u3.
// Workspace (4B units): ua,ub,hd [N*32] u32; wbf [3*2048]; rowptr[N+1];
//   rank[E]; cnt_int[N]; dinv[N]; bsum[256]; csr[E] u32; pooled[64*64];
//   gcnt[64]; flag[1]
// ---------------------------------------------------------------------------

__device__ __forceinline__ unsigned int pack_bf16(float a, float b) {
    unsigned int ua = __float_as_uint(a), ub = __float_as_uint(b);
    ua = (ua + 0x7FFFu + ((ua >> 16) & 1u)) >> 16;       // RNE
    ub = (ub + 0x7FFFu + ((ub >> 16) & 1u)) >> 16;
    return ua | (ub << 16);
}
__device__ __forceinline__ float bf_lo(unsigned int w) {
    return __uint_as_float(w << 16);
}
__device__ __forceinline__ float bf_hi(unsigned int w) {
    return __uint_as_float(w & 0xFFFF0000u);
}

__global__ __launch_bounds__(256) void k_init(int* __restrict__ cnt_int,
                                              float* __restrict__ pooled,
                                              int* __restrict__ flag, int N) {
    int i = blockIdx.x * 256 + threadIdx.x;
    if (i < N) cnt_int[i] = 0;
    if (i < NGRAPH * FEAT) pooled[i] = 0.f;
    if (i == 0) *flag = 0;
}

// WbfT[m][c][k]: packed bf16 pairs (k even|odd), transposed from W[k][c]
__global__ __launch_bounds__(256) void k_wcvt(const float* __restrict__ W1,
                                              const float* __restrict__ W2,
                                              const float* __restrict__ W3,
                                              unsigned int* __restrict__ wt) {
    int t = blockIdx.x * 256 + threadIdx.x;
    if (t >= 3 * 2048) return;
    int m = t >> 11, w = t & 2047;
    int c = w >> 5, kw = w & 31;
    const float* W = (m == 0) ? W1 : ((m == 1) ? W2 : W3);
    wt[t] = pack_bf16(W[(2 * kw) * 64 + c], W[(2 * kw + 1) * 64 + c]);
}

// Stream-convert x (f32) -> u (bf16x2). Thread handles 8 features.
__global__ __launch_bounds__(256) void k_xcvt(const float* __restrict__ x,
                                              unsigned int* __restrict__ u, int n8) {
    int t = blockIdx.x * 256 + threadIdx.x;
    if (t >= n8) return;
    const float4 a = *(const float4*)(x + (size_t)t * 8);
    const float4 b = *(const float4*)(x + (size_t)t * 8 + 4);
    uint4 p;
    p.x = pack_bf16(a.x, a.y);
    p.y = pack_bf16(a.z, a.w);
    p.z = pack_bf16(b.x, b.y);
    p.w = pack_bf16(b.z, b.w);
    *(uint4*)(u + (size_t)t * 4) = p;
}

// Detect how the bool supernode_mask was pushed to device.
__global__ __launch_bounds__(256) void k_detect(const unsigned int* __restrict__ m,
                                                int nwords, int* __restrict__ flag) {
    int i = blockIdx.x * 256 + threadIdx.x;
    if (i >= nwords) return;
    unsigned int w = m[i];
    if (w == 0x3F800000u) atomicOr(flag, 2);
    else if (w > 1u) atomicOr(flag, 1);
}

__device__ __forceinline__ bool read_mask(const void* sm, int i, int fl) {
    if (fl & 2) return ((const float*)sm)[i] != 0.f;
    if (fl & 1) return ((const unsigned char*)sm)[i] != 0;
    return ((const int*)sm)[i] != 0;
}

// count in-degree AND capture each edge's rank within its dst run.
__global__ __launch_bounds__(256) void k_count(const int* __restrict__ ei,
                                               int* __restrict__ cnt_int,
                                               int* __restrict__ rank, int E) {
    int e = blockIdx.x * 256 + threadIdx.x;
    if (e >= E) return;
    rank[e] = atomicAdd(&cnt_int[ei[E + e]], 1);
}

// --- 3-phase parallel exclusive scan ---------------------------------------
__global__ __launch_bounds__(256) void k_scan1(const int* __restrict__ cnt,
                                               int* __restrict__ rowptr,
                                               int* __restrict__ bsum, int N) {
    __shared__ int woff[4];
    int t = threadIdx.x, lane = t & 63, wid = t >> 6;
    int i = blockIdx.x * 256 + t;
    int orig = (i < N) ? cnt[i] : 0;
    int v = orig;
#pragma unroll
    for (int off = 1; off < 64; off <<= 1) {
        int u = __shfl_up(v, off);
        if (lane >= off) v += u;
    }
    if (lane == 63) woff[wid] = v;
    __syncthreads();
    if (t == 0) {
        int a = 0;
#pragma unroll
        for (int w = 0; w < 4; ++w) { int b = woff[w]; woff[w] = a; a += b; }
    }
    __syncthreads();
    int excl = woff[wid] + v - orig;
    if (i < N) rowptr[i] = excl;
    if (t == 255) bsum[blockIdx.x] = woff[3] + v;
}

__global__ __launch_bounds__(256) void k_scan2(int* __restrict__ bsum, int nb) {
    __shared__ int woff[4];
    int t = threadIdx.x, lane = t & 63, wid = t >> 6;
    int orig = (t < nb) ? bsum[t] : 0;
    int v = orig;
#pragma unroll
    for (int off = 1; off < 64; off <<= 1) {
        int u = __shfl_up(v, off);
        if (lane >= off) v += u;
    }
    if (lane == 63) woff[wid] = v;
    __syncthreads();
    if (t == 0) {
        int a = 0;
#pragma unroll
        for (int w = 0; w < 4; ++w) { int b = woff[w]; woff[w] = a; a += b; }
    }
    __syncthreads();
    if (t < nb) bsum[t] = woff[wid] + v - orig;
}

__global__ __launch_bounds__(256) void k_scan3(const int* __restrict__ cnt,
                                               const int* __restrict__ bsum,
                                               int* __restrict__ rowptr,
                                               float* __restrict__ dinv,
                                               int N, int E) {
    int i = blockIdx.x * 256 + threadIdx.x;
    if (i >= N) return;
    rowptr[i] += bsum[blockIdx.x];
    dinv[i] = rsqrtf((float)cnt[i] + 1.0f);
    if (i == 0) rowptr[N] = E;
}

// csr[rowptr[dst]+rank] = src | (w!=0)<<16      (single scattered 4B store)
__global__ __launch_bounds__(256) void k_fill(const int* __restrict__ ei,
                                              const float* __restrict__ emask,
                                              const int* __restrict__ rowptr,
                                              const int* __restrict__ rank,
                                              unsigned int* __restrict__ csr, int E) {
    int e = blockIdx.x * 256 + threadIdx.x;
    if (e >= E) return;
    int dst = ei[E + e];
    unsigned int word = (unsigned int)ei[e];
    if (emask[e] != 0.f) word |= 0x10000u;
    csr[rowptr[dst] + rank[e]] = word;
}

// Supernode-only: u[i] = bf16( sum_{w=1} x[src] ). Others already set by k_xcvt.
__global__ __launch_bounds__(256) void k_sup(const float* __restrict__ x,
                                             const int* __restrict__ rowptr,
                                             const unsigned int* __restrict__ csr,
                                             const void* __restrict__ sm,
                                             const int* __restrict__ flag,
                                             unsigned int* __restrict__ u, int N) {
    int t = blockIdx.x * 256 + threadIdx.x;
    int i = t >> 6, lane = t & 63;
    if (i >= N) return;
    int fl = *flag;
    if (!read_mask(sm, i, fl)) return;
    int g = lane >> 4, q = lane & 15;
    int r0 = rowptr[i], r1 = rowptr[i + 1];
    float4 acc = {0.f, 0.f, 0.f, 0.f};
    for (int j0 = r0; j0 < r1; j0 += 64) {
        int cnt = min(64, r1 - j0);
        unsigned int w_l = (lane < cnt) ? csr[j0 + lane] : 0u;
        int rounds4 = (cnt + 3) & ~3;
#pragma unroll 2
        for (int j = 0; j < rounds4; j += 4) {
            unsigned int wd = __shfl(w_l, j + g);
            if (wd & 0x10000u) {
                int s = (int)(wd & 0xFFFFu);
                const float4 v = *(const float4*)(x + (size_t)s * FEAT + q * 4);
                acc.x += v.x; acc.y += v.y; acc.z += v.z; acc.w += v.w;
            }
        }
    }
#pragma unroll
    for (int m = 16; m < 64; m <<= 1) {
        acc.x += __shfl_xor(acc.x, m);
        acc.y += __shfl_xor(acc.y, m);
        acc.z += __shfl_xor(acc.z, m);
        acc.w += __shfl_xor(acc.w, m);
    }
    if (g == 0) {
        uint2 p;
        p.x = pack_bf16(acc.x, acc.y);
        p.y = pack_bf16(acc.z, acc.w);
        *(uint2*)(u + (size_t)i * 32 + q * 2) = p;
    }
}

// MFMA GEMM: hd[r][:] = bf16( dinv[r] * (u[r][:] @ W) ), one 16x64 tile/wave.
__global__ __launch_bounds__(256) void k_gemm_mfma(const unsigned int* __restrict__ u_in,
                                                   const unsigned int* __restrict__ wbfT,
                                                   const float* __restrict__ dinv,
                                                   unsigned int* __restrict__ hd, int N) {
    int wid = threadIdx.x >> 6, lane = threadIdx.x & 63;
    int row0 = (blockIdx.x * 4 + wid) * 16;
    if (row0 >= N) return;
    int r = lane & 15, half = lane >> 4;
    f32x4 acc0 = {0.f, 0.f, 0.f, 0.f}, acc1 = acc0, acc2 = acc0, acc3 = acc0;
#pragma unroll
    for (int ks = 0; ks < 2; ++ks) {
        FragU a;
        a.u4 = *(const uint4*)(u_in + (size_t)(row0 + r) * 32 + ks * 16 + half * 4);
        FragU b0, b1, b2, b3;
        b0.u4 = *(const uint4*)(wbfT + (0 * 16 + r) * 32 + ks * 16 + half * 4);
        b1.u4 = *(const uint4*)(wbfT + (1 * 16 + r) * 32 + ks * 16 + half * 4);
        b2.u4 = *(const uint4*)(wbfT + (2 * 16 + r) * 32 + ks * 16 + half * 4);
        b3.u4 = *(const uint4*)(wbfT + (3 * 16 + r) * 32 + ks * 16 + half * 4);
        acc0 = __builtin_amdgcn_mfma_f32_16x16x32_bf16(a.h, b0.h, acc0, 0, 0, 0);
        acc1 = __builtin_amdgcn_mfma_f32_16x16x32_bf16(a.h, b1.h, acc1, 0, 0, 0);
        acc2 = __builtin_amdgcn_mfma_f32_16x16x32_bf16(a.h, b2.h, acc2, 0, 0, 0);
        acc3 = __builtin_amdgcn_mfma_f32_16x16x32_bf16(a.h, b3.h, acc3, 0, 0, 0);
    }
    float dd0 = dinv[row0 + half * 4 + 0];
    float dd1 = dinv[row0 + half * 4 + 1];
    float dd2 = dinv[row0 + half * 4 + 2];
    float dd3 = dinv[row0 + half * 4 + 3];
#pragma unroll
    for (int t = 0; t < 4; ++t) {
        const f32x4 acc = (t == 0) ? acc0 : (t == 1) ? acc1 : (t == 2) ? acc2 : acc3;
        float v0 = acc[0] * dd0, v1 = acc[1] * dd1, v2 = acc[2] * dd2, v3 = acc[3] * dd3;
        float o0 = __shfl_xor(v0, 1), o1 = __shfl_xor(v1, 1),
              o2 = __shfl_xor(v2, 1), o3 = __shfl_xor(v3, 1);
        if ((r & 1) == 0) {
            size_t base = (size_t)(row0 + half * 4) * 32 + t * 8 + (r >> 1);
            hd[base + 0 * 32] = pack_bf16(v0, o0);
            hd[base + 1 * 32] = pack_bf16(v1, o1);
            hd[base + 2 * 32] = pack_bf16(v2, o2);
            hd[base + 3 * 32] = pack_bf16(v3, o3);
        }
    }
}

// Wave per node, 8 edge-groups x 8 lanes, uint4 (16B) row chunks.
// u_out = bf16([relu]( dinv[i]*(sum_e hd[src] + hd[i]) + b ))
__global__ __launch_bounds__(256) void k_gather(const unsigned int* __restrict__ hd,
                                                const float* __restrict__ b,
                                                const float* __restrict__ dinv,
                                                const int* __restrict__ rowptr,
                                                const unsigned int* __restrict__ csr,
                                                unsigned int* __restrict__ u_out,
                                                int N, int do_relu) {
    int t = blockIdx.x * 256 + threadIdx.x;
    int i = t >> 6, lane = t & 63;
    if (i >= N) return;
    int g = lane >> 3, q = lane & 7;
    int r0 = rowptr[i], r1 = rowptr[i + 1];
    float acc[8] = {0.f, 0.f, 0.f, 0.f, 0.f, 0.f, 0.f, 0.f};
    for (int j0 = r0; j0 < r1; j0 += 64) {
        int cnt = min(64, r1 - j0);
        int s_l = (lane < cnt) ? (int)(csr[j0 + lane] & 0xFFFFu) : 0;
        int rounds8 = (cnt + 7) & ~7;
#pragma unroll 2
        for (int j = 0; j < rounds8; j += 8) {
            int jj = j + g;
            int s = __shfl(s_l, jj);
            if (jj < cnt) {
                const uint4 v = *(const uint4*)(hd + (size_t)s * 32 + q * 4);
                acc[0] += bf_lo(v.x); acc[1] += bf_hi(v.x);
                acc[2] += bf_lo(v.y); acc[3] += bf_hi(v.y);
                acc[4] += bf_lo(v.z); acc[5] += bf_hi(v.z);
                acc[6] += bf_lo(v.w); acc[7] += bf_hi(v.w);
            }
        }
    }
#pragma unroll
    for (int m = 8; m < 64; m <<= 1) {
#pragma unroll
        for (int k = 0; k < 8; ++k) acc[k] += __shfl_xor(acc[k], m);
    }
    if (g == 0) {
        float dd = dinv[i];
        const uint4 hv = *(const uint4*)(hd + (size_t)i * 32 + q * 4);
        const float4 b0 = *(const float4*)(b + q * 8);
        const float4 b1 = *(const float4*)(b + q * 8 + 4);
        float r[8];
        r[0] = (acc[0] + bf_lo(hv.x)) * dd + b0.x;
        r[1] = (acc[1] + bf_hi(hv.x)) * dd + b0.y;
        r[2] = (acc[2] + bf_lo(hv.y)) * dd + b0.z;
        r[3] = (acc[3] + bf_hi(hv.y)) * dd + b0.w;
        r[4] = (acc[4] + bf_lo(hv.z)) * dd + b1.x;
        r[5] = (acc[5] + bf_hi(hv.z)) * dd + b1.y;
        r[6] = (acc[6] + bf_lo(hv.w)) * dd + b1.z;
        r[7] = (acc[7] + bf_hi(hv.w)) * dd + b1.w;
        if (do_relu) {
#pragma unroll
            for (int k = 0; k < 8; ++k) r[k] = fmaxf(r[k], 0.f);
        }
        uint4 p;
        p.x = pack_bf16(r[0], r[1]);
        p.y = pack_bf16(r[2], r[3]);
        p.z = pack_bf16(r[4], r[5]);
        p.w = pack_bf16(r[6], r[7]);
        *(uint4*)(u_out + (size_t)i * 32 + q * 4) = p;
    }
}

__device__ __forceinline__ int lbound(const int* a, int n, int key) {
    int lo = 0, hi = n;
    while (lo < hi) {
        int mid = (lo + hi) >> 1;
        if (a[mid] < key) lo = mid + 1; else hi = mid;
    }
    return lo;
}

// 8 blocks per graph; partial sums atomically added to pooled. xb is bf16x2.
__global__ __launch_bounds__(256) void k_pool(const unsigned int* __restrict__ xb,
                                              const int* __restrict__ batch,
                                              float* __restrict__ pooled,
                                              float* __restrict__ gcnt, int N) {
    int g = blockIdx.x >> 3, c = blockIdx.x & (POOL_CHUNKS - 1);
    int lo = lbound(batch, N, g);
    int hi = lbound(batch, N, g + 1);
    int len = hi - lo;
    int t = threadIdx.x, lane = t & 63, sub = t >> 6;
    if (c == 0 && t == 0) gcnt[g] = (float)len;
    int a = lo + (int)(((long long)len * c) / POOL_CHUNKS);
    int bnd = lo + (int)(((long long)len * (c + 1)) / POOL_CHUNKS);
    float s = 0.f;
    int w = lane >> 1;
    bool hi_half = lane & 1;
    for (int i = a + sub; i < bnd; i += 4) {
        unsigned int word = xb[(size_t)i * 32 + w];
        s += hi_half ? bf_hi(word) : bf_lo(word);
    }
    __shared__ float red[4][64];
    red[sub][lane] = s;
    __syncthreads();
    if (sub == 0) {
        float tot = red[0][lane] + red[1][lane] + red[2][lane] + red[3][lane];
        unsafeAtomicAdd(&pooled[g * FEAT + lane], tot);
    }
}

// out[g][cls] = (pooled[g]/gcnt[g]) . Wl[:,cls] + bl[cls]
__global__ __launch_bounds__(640) void k_logits(const float* __restrict__ pooled,
                                                const float* __restrict__ gcnt,
                                                const float* __restrict__ Wl,
                                                const float* __restrict__ bl,
                                                float* __restrict__ out) {
    int t = threadIdx.x;
    if (t >= NGRAPH * 10) return;
    int g = t / 10, cls = t % 10;
    float inv = 1.f / fmaxf(gcnt[g], 1.f);
    float s = 0.f;
#pragma unroll
    for (int f = 0; f < 64; ++f) s += pooled[g * 64 + f] * Wl[f * 10 + cls];
    out[t] = s * inv + bl[cls];
}

extern "C" void kernel_launch(void* const* d_in, const int* in_sizes, int n_in,
                              void* d_out, int out_size, void* d_ws, size_t ws_size,
                              hipStream_t stream) {
    const float* x = (const float*)d_in[0];
    const int* ei = (const int*)d_in[1];
    const void* sm = d_in[2];
    const float* emask = (const float*)d_in[3];
    const int* batch = (const int*)d_in[4];
    const float* W1 = (const float*)d_in[5];
    const float* b1 = (const float*)d_in[6];
    const float* W2 = (const float*)d_in[7];
    const float* b2 = (const float*)d_in[8];
    const float* W3 = (const float*)d_in[9];
    const float* b3 = (const float*)d_in[10];
    const float* Wl = (const float*)d_in[11];
    const float* bl = (const float*)d_in[12];

    const int N = in_sizes[0] / FEAT;   // 50000 (< 65536; 16 | N)
    const int E = in_sizes[1] / 2;

    float* wsf = (float*)d_ws;
    size_t off = 0;
    unsigned int* ua = (unsigned int*)(wsf + off); off += (size_t)N * 32;
    unsigned int* ub = (unsigned int*)(wsf + off); off += (size_t)N * 32;
    unsigned int* hd = (unsigned int*)(wsf + off); off += (size_t)N * 32;
    unsigned int* wbf = (unsigned int*)(wsf + off); off += 3 * 2048;
    int* rowptr = (int*)(wsf + off);  off += N + 1;
    int* rank = (int*)(wsf + off);    off += E;
    int* cnt_int = (int*)(wsf + off); off += N;
    float* dinv = wsf + off;          off += N;
    int* bsum = (int*)(wsf + off);    off += 256;
    unsigned int* csr = (unsigned int*)(wsf + off); off += E;
    float* pooled = wsf + off;        off += NGRAPH * FEAT;
    float* gcnt = wsf + off;          off += NGRAPH;
    int* flag = (int*)(wsf + off);

    const int nblocks = (N + 255) / 256;
    const int eblocks = (E + 255) / 256;
    const int wblocks = (N * 64 + 255) / 256;
    const int gemm_blocks = (N / 16 + 3) / 4;
    const int detect_blocks = (N / 4 + 255) / 256;
    const int xcvt_blocks = (N * 8 + 255) / 256;

    k_init<<<nblocks, 256, 0, stream>>>(cnt_int, pooled, flag, N);
    k_wcvt<<<24, 256, 0, stream>>>(W1, W2, W3, wbf);
    k_xcvt<<<xcvt_blocks, 256, 0, stream>>>(x, ua, N * 8);
    k_detect<<<detect_blocks, 256, 0, stream>>>((const unsigned int*)sm, N / 4, flag);
    k_count<<<eblocks, 256, 0, stream>>>(ei, cnt_int, rank, E);
    k_scan1<<<nblocks, 256, 0, stream>>>(cnt_int, rowptr, bsum, N);
    k_scan2<<<1, 256, 0, stream>>>(bsum, nblocks);
    k_scan3<<<nblocks, 256, 0, stream>>>(cnt_int, bsum, rowptr, dinv, N, E);
    k_fill<<<eblocks, 256, 0, stream>>>(ei, emask, rowptr, rank, csr, E);
    k_sup<<<wblocks, 256, 0, stream>>>(x, rowptr, csr, sm, flag, ua, N);

    // layer 1
    k_gemm_mfma<<<gemm_blocks, 256, 0, stream>>>(ua, wbf + 0 * 2048, dinv, hd, N);
    k_gather<<<wblocks, 256, 0, stream>>>(hd, b1, dinv, rowptr, csr, ub, N, 1);
    // layer 2
    k_gemm_mfma<<<gemm_blocks, 256, 0, stream>>>(ub, wbf + 1 * 2048, dinv, hd, N);
    k_gather<<<wblocks, 256, 0, stream>>>(hd, b2, dinv, rowptr, csr, ua, N, 1);
    // layer 3
    k_gemm_mfma<<<gemm_blocks, 256, 0, stream>>>(ua, wbf + 2 * 2048, dinv, hd, N);
    k_gather<<<wblocks, 256, 0, stream>>>(hd, b3, dinv, rowptr, csr, ub, N, 0);

    k_pool<<<NGRAPH * POOL_CHUNKS, 256, 0, stream>>>(ub, batch, pooled, gcnt, N);
    k_logits<<<1, 640, 0, stream>>>(pooled, gcnt, Wl, bl, (float*)d_out);
}